// Round 15
// baseline (212.768 us; speedup 1.0000x reference)
//
#include <hip/hip_runtime.h>
#include <hip/hip_cooperative_groups.h>

namespace cg = cooperative_groups;

typedef unsigned int u32;
typedef unsigned short u16;
typedef __attribute__((ext_vector_type(8))) short short8;
typedef __attribute__((ext_vector_type(4))) float f32x4;
typedef __attribute__((ext_vector_type(16))) float f32x16;

#define BB 8
#define KK 32
#define SS 4096
#define HH 2048
#define DD 1024
#define NSC 16
#define SC_S 256
#define CH (BB * KK * HH)

// ws layout (bytes)
#define OFF_W16  0ull           // bf16 [b][k][s]          : 2 MiB
#define OFF_WB   (2ull << 20)   // bf16 [d][h] (W^T)       : 4 MiB
#define OFF_PART (6ull << 20)   // bf16 [sc][b][k][h]      : 16 MiB
#define OFF_PQ   (23ull << 20)  // bf16 [row][h] pooled    : 1 MiB
#define OFF_PROJ (24ull << 20)  // f32 [row][d]            : 1 MiB

__device__ __forceinline__ u16 f2bf(float x) {
  u32 u = __float_as_uint(x);
  return (u16)((u + 0x7fffu + ((u >> 16) & 1u)) >> 16);  // RNE
}

// ---------------------------------------------------------------------------
// k_all: single cooperative kernel, 256 blocks x 1024 thr (1 block/CU).
// Phases separated by grid.sync(); each phase keeps the grid-wide parallelism
// its R14 standalone version had (R12/R13 lesson: never shrink the grid).
// ---------------------------------------------------------------------------
__global__ __launch_bounds__(1024, 4) void k_all(const float* __restrict__ plan,
                                                 const void* __restrict__ own,
                                                 const float* __restrict__ W,
                                                 const float* __restrict__ bias,
                                                 const float* __restrict__ gamma,
                                                 const float* __restrict__ beta,
                                                 float* __restrict__ out,
                                                 u16* __restrict__ w16,
                                                 u16* __restrict__ WB,
                                                 u16* __restrict__ part,
                                                 u32* __restrict__ pq,
                                                 float* __restrict__ proj) {
  cg::grid_group grid = cg::this_grid();
  __shared__ float sP[4][16][64];   // proj K-quarter combine (16 KB)
  __shared__ float sLa[16], sLb[16];

  const int blk = blockIdx.x;
  const int t = threadIdx.x;
  const int w = t >> 6, l = t & 63;

  // ===== Phase A: prep (all wave-local — no intra-block barriers) =====
  if (w == 0) {
    // ---- weights role: bk = blk; lane l owns s in [l*64, l*64+64) ----
    u32 wd = ((const u32*)own)[l];
    bool wordok = (wd <= 1u) || (wd == 0x3f800000u);
    unsigned long long m = __ballot(wordok);
    const int mode = (m == ~0ull) ? 1 : 0;  // 1: 4-byte elems, 0: bytes

    const size_t base = (size_t)blk * SS + (size_t)l * 64;
    unsigned long long bits = 0;
    if (mode == 0) {
      const uint4* p = (const uint4*)((const unsigned char*)own + base);
#pragma unroll
      for (int q = 0; q < 4; ++q) {
        uint4 v = p[q];
        u32 wa[4] = {v.x, v.y, v.z, v.w};
#pragma unroll
        for (int wj = 0; wj < 4; ++wj)
#pragma unroll
          for (int bj = 0; bj < 4; ++bj)
            if ((wa[wj] >> (8 * bj)) & 0xffu)
              bits |= 1ull << (q * 16 + wj * 4 + bj);
      }
    } else {
      const u32* p = (const u32*)own + base;
#pragma unroll
      for (int j = 0; j < 64; ++j)
        if (p[j] != 0u) bits |= 1ull << j;
    }
    int cnt = __popcll(bits);
#pragma unroll
    for (int off = 1; off < 64; off <<= 1) cnt += __shfl_xor(cnt, off);
    const float inv = 1.0f / fmaxf((float)cnt, 1.0f);
    const u32 hv = (u32)f2bf(inv);

    u32* wo = (u32*)w16 + ((size_t)blk * SS + (size_t)l * 64) / 2;
#pragma unroll
    for (int q = 0; q < 8; ++q) {
      u32 ww[4];
#pragma unroll
      for (int d = 0; d < 4; ++d) {
        int j = q * 8 + d * 2;
        u32 lo = ((bits >> j) & 1ull) ? hv : 0u;
        u32 hi = ((bits >> (j + 1)) & 1ull) ? hv : 0u;
        ww[d] = lo | (hi << 16);
      }
      uint4 o = {ww[0], ww[1], ww[2], ww[3]};
      ((uint4*)wo)[q] = o;
    }
  } else {
    // ---- W-transpose role: wave-task = 16-h strip x 64-d tile ----
    int wt = blk * 15 + (w - 1);    // 3840 slots >= 2048 tasks
    if (wt < 2048) {
      int hb = (wt >> 4) * 16;
      int d0 = (wt & 15) * 64;
      u16 rg[16];
#pragma unroll
      for (int j = 0; j < 16; ++j)
        rg[j] = f2bf(W[(size_t)(hb + j) * DD + d0 + l]);  // coalesced reads
      u16* dst = WB + (size_t)(d0 + l) * HH + hb;         // 32B/lane writes
#pragma unroll
      for (int q = 0; q < 2; ++q) {
        u32 ww[4];
#pragma unroll
        for (int d = 0; d < 4; ++d) {
          int j = q * 8 + d * 2;
          ww[d] = (u32)rg[j] | ((u32)rg[j + 1] << 16);
        }
        uint4 o = {ww[0], ww[1], ww[2], ww[3]};
        ((uint4*)dst)[q] = o;
      }
    }
  }

  grid.sync();

  // ===== Phase B: pool (R12's verified ~42-45us core, same block map) =====
  {
    const int hcb = blk & 1, sc = (blk >> 1) & 15, b = blk >> 5;
    const int lc = l & 31, half = l >> 5;
    const int h0 = hcb * 1024 + w * 64;
    const int s0 = sc * SC_S;

    const float* pb = plan + (size_t)b * SS * HH + h0 + lc;
    const u16* wa = w16 + (size_t)(b * KK + lc) * SS;

    f32x16 acc0, acc1;
#pragma unroll
    for (int r = 0; r < 16; ++r) { acc0[r] = 0.0f; acc1[r] = 0.0f; }

    for (int step = 0; step < SC_S / 16; ++step) {
      const int sb = s0 + step * 16 + half * 8;
      short8 a = *(const short8*)(wa + sb);
      const float* col = pb + (size_t)sb * HH;
      float f0[8], f1[8];
#pragma unroll
      for (int j = 0; j < 8; ++j) {
        f0[j] = col[(size_t)j * HH];
        f1[j] = col[(size_t)j * HH + 32];
      }
      short8 b0, b1;
#pragma unroll
      for (int j = 0; j < 8; ++j) {
        b0[j] = (short)f2bf(f0[j]);
        b1[j] = (short)f2bf(f1[j]);
      }
      acc0 = __builtin_amdgcn_mfma_f32_32x32x16_bf16(a, b0, acc0, 0, 0, 0);
      acc1 = __builtin_amdgcn_mfma_f32_32x32x16_bf16(a, b1, acc1, 0, 0, 0);
    }

    u16* po = part + ((size_t)sc * BB + b) * KK * HH + h0 + lc;
#pragma unroll
    for (int r = 0; r < 16; ++r) {
      int krow = (r & 3) + 8 * (r >> 2) + 4 * half;
      po[(size_t)krow * HH] = f2bf(acc0[r]);
      po[(size_t)krow * HH + 32] = f2bf(acc1[r]);
    }
  }

  grid.sync();

  // ===== Phase C: reduce (1 output per thread, coalesced) =====
  {
    const int i = blk * 1024 + t;   // 262144 = 256 rows * 1024 h-pairs
    const int row = i >> 10, hp = i & 1023;
    const u16* p = part + (size_t)row * HH + 2 * hp;
    float lo = 0.f, hi = 0.f;
#pragma unroll
    for (int sc = 0; sc < NSC; ++sc) {
      u32 v = *(const u32*)(p + (size_t)sc * CH);
      lo += __uint_as_float((v & 0xffffu) << 16);
      hi += __uint_as_float(v & 0xffff0000u);
    }
    pq[i] = (u32)f2bf(lo) | ((u32)f2bf(hi) << 16);
  }

  grid.sync();

  // ===== Phase D: proj (256-wide grid kept; K split 4-way across waves) ====
  {
    const int rt = blk >> 4, cq = blk & 15;
    const int kq = w & 3, cw = w >> 2;
    const int lr = l & 15, lg = l >> 4;
    const int r0 = rt * 16, c0 = cq * 64;

    const u16* pa = (const u16*)pq + (size_t)(r0 + lr) * HH + kq * 512 + lg * 8;
    const u16* pw = WB + (size_t)(c0 + cw * 16 + lr) * HH + kq * 512 + lg * 8;
    f32x4 acc = (f32x4){0.f, 0.f, 0.f, 0.f};
#pragma unroll
    for (int slab = 0; slab < 16; ++slab) {
      short8 a = *(const short8*)(pa + slab * 32);
      short8 bv = *(const short8*)(pw + slab * 32);
      acc = __builtin_amdgcn_mfma_f32_16x16x32_bf16(a, bv, acc, 0, 0, 0);
    }
    // C layout (16x16x32): col = lane&15, row = lg*4 + reg
#pragma unroll
    for (int j = 0; j < 4; ++j)
      sP[kq][lg * 4 + j][cw * 16 + lr] = acc[j];
    __syncthreads();
    {
      int rr = t >> 6, cc = t & 63;
      float v = sP[0][rr][cc] + sP[1][rr][cc] + sP[2][rr][cc] + sP[3][rr][cc]
              + bias[c0 + cc];
      proj[(size_t)(r0 + rr) * DD + c0 + cc] = v;
    }
  }

  grid.sync();

  // ===== Phase E: LayerNorm (1 row per block, exact ref math) =====
  {
    const int row = blk;
    float v = proj[(size_t)row * DD + t];
    float s1 = v, s2 = v * v;
#pragma unroll
    for (int off = 1; off < 64; off <<= 1) {
      s1 += __shfl_xor(s1, off);
      s2 += __shfl_xor(s2, off);
    }
    if (l == 0) { sLa[w] = s1; sLb[w] = s2; }
    __syncthreads();
    float S1 = 0.f, S2 = 0.f;
#pragma unroll
    for (int q = 0; q < 16; ++q) { S1 += sLa[q]; S2 += sLb[q]; }
    const float mu = S1 * (1.0f / DD);
    const float var = S2 * (1.0f / DD) - mu * mu;
    const float rs = rsqrtf(var + 1e-5f);
    out[(size_t)row * DD + t] = (v - mu) * rs * gamma[t] + beta[t];
  }
}

// ---------------------------------------------------------------------------

extern "C" void kernel_launch(void* const* d_in, const int* in_sizes, int n_in,
                              void* d_out, int out_size, void* d_ws, size_t ws_size,
                              hipStream_t stream) {
  (void)in_sizes; (void)n_in; (void)out_size; (void)ws_size;
  const float* plan  = (const float*)d_in[0];
  const void*  own   = d_in[1];
  const float* W     = (const float*)d_in[2];
  const float* bias  = (const float*)d_in[3];
  const float* gamma = (const float*)d_in[4];
  const float* beta  = (const float*)d_in[5];
  float* out = (float*)d_out;
  char* ws = (char*)d_ws;

  u16*   w16  = (u16*)(ws + OFF_W16);
  u16*   WB   = (u16*)(ws + OFF_WB);
  u16*   part = (u16*)(ws + OFF_PART);
  u32*   pq   = (u32*)(ws + OFF_PQ);
  float* proj = (float*)(ws + OFF_PROJ);

  void* args[] = {(void*)&plan, (void*)&own, (void*)&W, (void*)&bias,
                  (void*)&gamma, (void*)&beta, (void*)&out, (void*)&w16,
                  (void*)&WB, (void*)&part, (void*)&pq, (void*)&proj};
  hipLaunchCooperativeKernel(reinterpret_cast<const void*>(k_all),
                             dim3(256), dim3(1024), args, 0, stream);
}

// Round 16
// 95.391 us; speedup vs baseline: 2.2305x; 2.2305x over previous
//
#include <hip/hip_runtime.h>

typedef unsigned int u32;
typedef unsigned short u16;
typedef unsigned char u8;
typedef unsigned long long u64;
typedef __attribute__((ext_vector_type(8))) short short8;
typedef __attribute__((ext_vector_type(4))) float f32x4;
typedef __attribute__((ext_vector_type(16))) float f32x16;

#define BB 8
#define KK 32
#define SS 4096
#define HH 2048
#define DD 1024
#define NSC 16       // s-chunks in pooling
#define SC_S 256     // s per chunk
#define CH (BB * KK * HH)  // partial-chunk stride (elements)

// ws layout (bytes)
#define OFF_WB   (2ull << 20)   // bf16 [d][h] (W^T)       : 4 MiB
#define OFF_PART (6ull << 20)   // bf16 [sc][b][k][h]      : 16 MiB
#define OFF_PQ   (23ull << 20)  // bf16 [row][h] pooled    : 1 MiB
#define OFF_PROJ (24ull << 20)  // f32 [row][d]            : 1 MiB

__device__ __forceinline__ u16 f2bf(float x) {
  u32 u = __float_as_uint(x);
  return (u16)((u + 0x7fffu + ((u >> 16) & 1u)) >> 16);  // RNE
}

// count of nonzero bytes in a u32
__device__ __forceinline__ int nzb(u32 x) {
  return __popc((((x & 0x7F7F7F7Fu) + 0x7F7F7F7Fu) | x) & 0x80808080u);
}

// ---------------------------------------------------------------------------
// k_pool: R12's verified ~45us core + INLINE ownership weights (kills the
// separate prep kernel + its graph gap). Phase 0: block computes its b's 32
// owner-counts (own is L2/L3-resident; redundant per block, ~130 ops/thread).
// Phase 1: identical MFMA loop; A-fragment = mask-select(bf16(1/cnt), 0) from
// 8 ownership bytes/lane — bit-identical to the old w16 path.
// Grid (2,16,8)=256 blocks x 1024 thr, 1 block/CU, no inter-block coupling.
// ---------------------------------------------------------------------------
__global__ __launch_bounds__(1024, 4) void k_pool(const float* __restrict__ plan,
                                                  const void* __restrict__ own,
                                                  u16* __restrict__ part) {
  __shared__ float s_inv[KK];
  __shared__ int s_mode;
  const int hcb = blockIdx.x, sc = blockIdx.y, b = blockIdx.z;
  const int t = threadIdx.x, wv = t >> 6, l = t & 63;
  const int lc = l & 31, half = l >> 5;

  // ---- Phase 0: ownership counts for batch b ----
  if (t < 64) {
    u32 wd = ((const u32*)own)[t];
    bool wordok = (wd <= 1u) || (wd == 0x3f800000u);
    unsigned long long m = __ballot(wordok);
    if (t == 0) s_mode = (m == ~0ull) ? 1 : 0;  // 1: 4-byte elems, 0: bytes
  }
  __syncthreads();
  const int mode = s_mode;

  {
    const int k = t >> 5, g = t & 31;  // 32 threads per k-row
    int cnt = 0;
    if (mode == 0) {
      const uint4* p = (const uint4*)((const u8*)own + (size_t)(b * KK + k) * SS);
#pragma unroll
      for (int i = 0; i < 8; ++i) {
        uint4 v = p[g * 8 + i];
        cnt += nzb(v.x) + nzb(v.y) + nzb(v.z) + nzb(v.w);
      }
    } else {
      const uint4* p = (const uint4*)((const u32*)own + (size_t)(b * KK + k) * SS);
#pragma unroll
      for (int i = 0; i < 32; ++i) {
        uint4 v = p[g * 32 + i];
        cnt += (v.x != 0u) + (v.y != 0u) + (v.z != 0u) + (v.w != 0u);
      }
    }
#pragma unroll
    for (int off = 1; off < 32; off <<= 1) cnt += __shfl_xor(cnt, off);
    if (g == 0) s_inv[k] = 1.0f / fmaxf((float)cnt, 1.0f);
  }
  __syncthreads();

  // ---- Phase 1: MFMA pooling (R12 core, frozen) ----
  const int h0 = hcb * 1024 + wv * 64;
  const int s0 = sc * SC_S;
  const float* pb = plan + (size_t)b * SS * HH + h0 + lc;
  const u16 hv = f2bf(s_inv[lc]);
  const u8* obl = (const u8*)own + (size_t)(b * KK + lc) * SS;
  const u32* owl = (const u32*)own + (size_t)(b * KK + lc) * SS;

  f32x16 acc0, acc1;
#pragma unroll
  for (int r = 0; r < 16; ++r) { acc0[r] = 0.0f; acc1[r] = 0.0f; }

  for (int step = 0; step < SC_S / 16; ++step) {
    const int sb = s0 + step * 16 + half * 8;
    // A: 8 ownership flags -> {hv, 0} bf16
    short8 a;
    if (mode == 0) {
      u64 msk = *(const u64*)(obl + sb);
#pragma unroll
      for (int j = 0; j < 8; ++j)
        a[j] = (short)(((msk >> (8 * j)) & 0xffull) ? hv : (u16)0);
    } else {
      uint4 w0 = *(const uint4*)(owl + sb);
      uint4 w1 = *(const uint4*)(owl + sb + 4);
      u32 wa[8] = {w0.x, w0.y, w0.z, w0.w, w1.x, w1.y, w1.z, w1.w};
#pragma unroll
      for (int j = 0; j < 8; ++j)
        a[j] = (short)(wa[j] ? hv : (u16)0);
    }
    // B: lane lc = h-col; two 32-h tiles; 8 s-rows each (stride HH)
    const float* col = pb + (size_t)sb * HH;
    float f0[8], f1[8];
#pragma unroll
    for (int j = 0; j < 8; ++j) {
      f0[j] = col[(size_t)j * HH];
      f1[j] = col[(size_t)j * HH + 32];
    }
    short8 b0, b1;
#pragma unroll
    for (int j = 0; j < 8; ++j) {
      b0[j] = (short)f2bf(f0[j]);
      b1[j] = (short)f2bf(f1[j]);
    }
    acc0 = __builtin_amdgcn_mfma_f32_32x32x16_bf16(a, b0, acc0, 0, 0, 0);
    acc1 = __builtin_amdgcn_mfma_f32_32x32x16_bf16(a, b1, acc1, 0, 0, 0);
  }

  // C layout: col = lane&31, row = (reg&3) + 8*(reg>>2) + 4*(lane>>5)
  u16* po = part + ((size_t)sc * BB + b) * KK * HH + h0 + lc;
#pragma unroll
  for (int r = 0; r < 16; ++r) {
    int krow = (r & 3) + 8 * (r >> 2) + 4 * half;
    po[(size_t)krow * HH] = f2bf(acc0[r]);
    po[(size_t)krow * HH + 32] = f2bf(acc1[r]);
  }
}

// ---------------------------------------------------------------------------
// k_mid: dual-role. Blocks [0,1024): fold 16 bf16 partials -> pq (R14 reduce).
// Blocks [1024,1536): W[h][d] -> WB[d][h] bf16 via LDS 64x64 transpose
// (independent work; WB only consumed by k_proj downstream).
// ---------------------------------------------------------------------------
__global__ __launch_bounds__(256) void k_mid(const u16* __restrict__ part,
                                             u32* __restrict__ pq,
                                             const float* __restrict__ W,
                                             u16* __restrict__ WB) {
  __shared__ float lds[64][65];
  const int t = threadIdx.x;

  if (blockIdx.x < 1024) {
    const int i = blockIdx.x * 256 + t;  // 256 rows * 1024 h-pairs
    const int row = i >> 10, hp = i & 1023;
    const u16* p = part + (size_t)row * HH + 2 * hp;
    float lo = 0.f, hi = 0.f;
#pragma unroll
    for (int sc = 0; sc < NSC; ++sc) {
      u32 v = *(const u32*)(p + (size_t)sc * CH);
      lo += __uint_as_float((v & 0xffffu) << 16);
      hi += __uint_as_float(v & 0xffff0000u);
    }
    pq[i] = (u32)f2bf(lo) | ((u32)f2bf(hi) << 16);
  } else {
    const int bidx = blockIdx.x - 1024;  // 0..511
    const int hb = (bidx & 31) * 64, db = (bidx >> 5) * 64;
    const int x = t & 63, y = t >> 6;
#pragma unroll
    for (int j = 0; j < 16; ++j) {
      int r = y + 4 * j;
      lds[r][x] = W[(size_t)(hb + r) * DD + db + x];
    }
    __syncthreads();
#pragma unroll
    for (int j = 0; j < 16; ++j) {
      int r = y + 4 * j;
      WB[(size_t)(db + r) * HH + hb + x] = f2bf(lds[x][r]);
    }
  }
}

// ---------------------------------------------------------------------------
// k_proj: 256-block MFMA projection (R14-proven ~6us; never shrink the grid).
// ---------------------------------------------------------------------------
__global__ __launch_bounds__(256) void k_proj(const u16* __restrict__ pq,
                                              const u16* __restrict__ WB,
                                              const float* __restrict__ bias,
                                              float* __restrict__ proj) {
  const int rt = blockIdx.x, ctg = blockIdx.y;
  const int t = threadIdx.x, w = t >> 6, l = t & 63;
  const int lr = l & 15, lg = l >> 4;
  const int r0 = rt * 16, c0 = (ctg * 4 + w) * 16;

  const u16* pa = pq + (size_t)(r0 + lr) * HH + lg * 8;
  const u16* pw = WB + (size_t)(c0 + lr) * HH + lg * 8;
  f32x4 acc = (f32x4){0.f, 0.f, 0.f, 0.f};
#pragma unroll 4
  for (int slab = 0; slab < 64; ++slab) {
    short8 a = *(const short8*)(pa + slab * 32);
    short8 bv = *(const short8*)(pw + slab * 32);
    acc = __builtin_amdgcn_mfma_f32_16x16x32_bf16(a, bv, acc, 0, 0, 0);
  }
  const float bs = bias[c0 + lr];
#pragma unroll
  for (int j = 0; j < 4; ++j)
    proj[(size_t)(r0 + lg * 4 + j) * DD + c0 + lr] = acc[j] + bs;
}

// ---------------------------------------------------------------------------
// k_ln: LayerNorm over D=1024, one block per row (exact ref math, f32).
// ---------------------------------------------------------------------------
__global__ __launch_bounds__(256) void k_ln(const float* __restrict__ proj,
                                            const float* __restrict__ gamma,
                                            const float* __restrict__ beta,
                                            float* __restrict__ out) {
  const int row = blockIdx.x, t = threadIdx.x;
  float4 v = ((const float4*)(proj + (size_t)row * DD))[t];
  float s1 = v.x + v.y + v.z + v.w;
  float s2 = v.x * v.x + v.y * v.y + v.z * v.z + v.w * v.w;
#pragma unroll
  for (int off = 1; off < 64; off <<= 1) {
    s1 += __shfl_xor(s1, off);
    s2 += __shfl_xor(s2, off);
  }
  __shared__ float a1[4], a2[4];
  if ((t & 63) == 0) { a1[t >> 6] = s1; a2[t >> 6] = s2; }
  __syncthreads();
  const float S1 = a1[0] + a1[1] + a1[2] + a1[3];
  const float S2 = a2[0] + a2[1] + a2[2] + a2[3];
  const float mu = S1 * (1.0f / DD);
  const float var = S2 * (1.0f / DD) - mu * mu;
  const float rs = rsqrtf(var + 1e-5f);
  float4 g = ((const float4*)gamma)[t];
  float4 be = ((const float4*)beta)[t];
  float4 o;
  o.x = (v.x - mu) * rs * g.x + be.x;
  o.y = (v.y - mu) * rs * g.y + be.y;
  o.z = (v.z - mu) * rs * g.z + be.z;
  o.w = (v.w - mu) * rs * g.w + be.w;
  ((float4*)(out + (size_t)row * DD))[t] = o;
}

// ---------------------------------------------------------------------------

extern "C" void kernel_launch(void* const* d_in, const int* in_sizes, int n_in,
                              void* d_out, int out_size, void* d_ws, size_t ws_size,
                              hipStream_t stream) {
  (void)in_sizes; (void)n_in; (void)out_size; (void)ws_size;
  const float* plan  = (const float*)d_in[0];
  const void*  own   = d_in[1];
  const float* W     = (const float*)d_in[2];
  const float* bias  = (const float*)d_in[3];
  const float* gamma = (const float*)d_in[4];
  const float* beta  = (const float*)d_in[5];
  float* out = (float*)d_out;
  char* ws = (char*)d_ws;

  u16*   WB   = (u16*)(ws + OFF_WB);
  u16*   part = (u16*)(ws + OFF_PART);
  u32*   pq   = (u32*)(ws + OFF_PQ);
  float* proj = (float*)(ws + OFF_PROJ);

  k_pool<<<dim3(2, NSC, BB), dim3(1024), 0, stream>>>(plan, own, part);
  k_mid<<<dim3(1536), dim3(256), 0, stream>>>(part, pq, W, WB);
  k_proj<<<dim3(16, 16), dim3(256), 0, stream>>>((const u16*)pq, WB, bias, proj);
  k_ln<<<dim3(BB * KK), dim3(256), 0, stream>>>(proj, gamma, beta, out);
}

// Round 17
// 91.866 us; speedup vs baseline: 2.3161x; 1.0384x over previous
//
#include <hip/hip_runtime.h>

typedef unsigned int u32;
typedef unsigned short u16;
typedef __attribute__((ext_vector_type(8))) short short8;
typedef __attribute__((ext_vector_type(4))) float f32x4;
typedef __attribute__((ext_vector_type(16))) float f32x16;

#define BB 8
#define KK 32
#define SS 4096
#define HH 2048
#define DD 1024
#define NSC 16       // s-chunks in pooling
#define SC_S 256     // s per chunk

// ws layout (bytes)
#define OFF_W16    0ull          // bf16 [b][k][s]        : 2 MiB
#define OFF_WB     (2ull << 20)  // bf16 [d][h] (W^T)     : 4 MiB
#define OFF_POOLED (6ull << 20)  // f32 [row][h] pooled   : 2 MiB (atomic acc)
#define OFF_PROJ   (8ull << 20)  // f32 [row][d]          : 1 MiB

__device__ __forceinline__ u16 f2bf(float x) {
  u32 u = __float_as_uint(x);
  return (u16)((u + 0x7fffu + ((u >> 16) & 1u)) >> 16);  // RNE
}

// ---------------------------------------------------------------------------
// k_prep: triple-role (R14 prep + pooled zeroing, per R10's proven pattern).
// Blocks [0,256): ownership -> bf16 weights w16[b][k][s].
// Blocks [256,768): W[h][d] -> WB[d][h] bf16 via LDS 64x64 transpose.
// Blocks [0,512): also zero 4KB of pooled each (2 MiB total, atomic target).
// ---------------------------------------------------------------------------
__global__ __launch_bounds__(256) void k_prep(const void* __restrict__ own,
                                              u16* __restrict__ w16,
                                              const float* __restrict__ W,
                                              u16* __restrict__ WB,
                                              float* __restrict__ pooled) {
  __shared__ float lds[64][65];
  const int t = threadIdx.x;

  if (blockIdx.x < 512) {
    f32x4 z = (f32x4){0.f, 0.f, 0.f, 0.f};
    ((f32x4*)pooled)[(size_t)blockIdx.x * 256 + t] = z;
  }

  if (blockIdx.x < BB * KK) {
    // ---- weights role ----
    const int bk = blockIdx.x;  // b*32 + k
    __shared__ int s_mode;
    __shared__ int s_wcnt[4];
    __shared__ float s_inv;

    if (t < 64) {
      u32 w = ((const u32*)own)[t];
      bool wordok = (w <= 1u) || (w == 0x3f800000u);
      unsigned long long m = __ballot(wordok);
      if (t == 0) s_mode = (m == ~0ull) ? 1 : 0;  // 1: 4-byte elems, 0: bytes
    }
    __syncthreads();
    const int mode = s_mode;

    u32 bits = 0;  // bit j = own[b][k][t*16 + j]
    const size_t base = (size_t)bk * SS + (size_t)t * 16;
    if (mode == 0) {
      uint4 v = *(const uint4*)((const unsigned char*)own + base);
      u32 wa[4] = {v.x, v.y, v.z, v.w};
#pragma unroll
      for (int w = 0; w < 4; ++w)
#pragma unroll
        for (int j = 0; j < 4; ++j)
          if ((wa[w] >> (8 * j)) & 0xffu) bits |= 1u << (4 * w + j);
    } else {
      const u32* p = (const u32*)own + base;
#pragma unroll
      for (int j = 0; j < 16; ++j)
        if (p[j] != 0u) bits |= 1u << j;
    }

    int cnt = __popc(bits);
#pragma unroll
    for (int off = 1; off < 64; off <<= 1) cnt += __shfl_xor(cnt, off);
    if ((t & 63) == 0) s_wcnt[t >> 6] = cnt;
    __syncthreads();
    if (t == 0) {
      int tot = s_wcnt[0] + s_wcnt[1] + s_wcnt[2] + s_wcnt[3];
      s_inv = 1.0f / fmaxf((float)tot, 1.0f);
    }
    __syncthreads();
    const u32 hv = (u32)f2bf(s_inv);

    u32 outw[8];
#pragma unroll
    for (int j = 0; j < 8; ++j) {
      u32 lo = ((bits >> (2 * j)) & 1u) ? hv : 0u;
      u32 hi = ((bits >> (2 * j + 1)) & 1u) ? hv : 0u;
      outw[j] = lo | (hi << 16);
    }
    u32* wo = (u32*)w16 + (size_t)bk * (SS / 2) + (size_t)t * 8;
    uint4 o0 = {outw[0], outw[1], outw[2], outw[3]};
    uint4 o1 = {outw[4], outw[5], outw[6], outw[7]};
    ((uint4*)wo)[0] = o0;
    ((uint4*)wo)[1] = o1;
  } else {
    // ---- W-transpose role ----
    const int bidx = blockIdx.x - BB * KK;   // 0..511
    const int hb = (bidx & 31) * 64, db = (bidx >> 5) * 64;
    const int x = t & 63, y = t >> 6;
#pragma unroll
    for (int j = 0; j < 16; ++j) {
      int r = y + 4 * j;
      lds[r][x] = W[(size_t)(hb + r) * DD + db + x];
    }
    __syncthreads();
#pragma unroll
    for (int j = 0; j < 16; ++j) {
      int r = y + 4 * j;
      WB[(size_t)(db + r) * HH + hb + x] = f2bf(lds[x][r]);
    }
  }
}

// ---------------------------------------------------------------------------
// k_pool: the VERIFIED R12 core (42-45us, combined HBM+L3 roofline: R15's
// FETCH=157MB of a 268MB stream) with f32 atomicAdd epilogue into pooled —
// kills k_reduce + one graph gap. 16 sc-writers per address; R10 measured
// ~+8us for this on a weaker core. Grid (2,16,8)=256 blocks x 1024 thr.
// ---------------------------------------------------------------------------
__global__ __launch_bounds__(1024, 4) void k_pool(const float* __restrict__ plan,
                                                  const u16* __restrict__ w16,
                                                  float* __restrict__ pooled) {
  const int hcb = blockIdx.x, sc = blockIdx.y, b = blockIdx.z;
  const int t = threadIdx.x, wv = t >> 6, l = t & 63;
  const int lc = l & 31, half = l >> 5;
  const int h0 = hcb * 1024 + wv * 64;
  const int s0 = sc * SC_S;

  const float* pb = plan + (size_t)b * SS * HH + h0 + lc;
  const u16* wa = w16 + (size_t)(b * KK + lc) * SS;

  f32x16 acc0, acc1;
#pragma unroll
  for (int r = 0; r < 16; ++r) { acc0[r] = 0.0f; acc1[r] = 0.0f; }

  for (int step = 0; step < SC_S / 16; ++step) {
    const int sb = s0 + step * 16 + half * 8;
    short8 a = *(const short8*)(wa + sb);
    const float* col = pb + (size_t)sb * HH;
    float f0[8], f1[8];
#pragma unroll
    for (int j = 0; j < 8; ++j) {
      f0[j] = col[(size_t)j * HH];
      f1[j] = col[(size_t)j * HH + 32];
    }
    short8 b0, b1;
#pragma unroll
    for (int j = 0; j < 8; ++j) {
      b0[j] = (short)f2bf(f0[j]);
      b1[j] = (short)f2bf(f1[j]);
    }
    acc0 = __builtin_amdgcn_mfma_f32_32x32x16_bf16(a, b0, acc0, 0, 0, 0);
    acc1 = __builtin_amdgcn_mfma_f32_32x32x16_bf16(a, b1, acc1, 0, 0, 0);
  }

  // C layout: col = lane&31, row = (reg&3) + 8*(reg>>2) + 4*(lane>>5)
  float* po = pooled + (size_t)(b * KK) * HH + h0 + lc;
#pragma unroll
  for (int r = 0; r < 16; ++r) {
    int krow = (r & 3) + 8 * (r >> 2) + 4 * half;
    atomicAdd(&po[(size_t)krow * HH], acc0[r]);
    atomicAdd(&po[(size_t)krow * HH + 32], acc1[r]);
  }
}

// ---------------------------------------------------------------------------
// k_proj: 256-block MFMA projection, A from pooled f32 (cvt in-register,
// R10-proven reader; R14-proven grid shape — never shrink the grid).
// ---------------------------------------------------------------------------
__global__ __launch_bounds__(256) void k_proj(const float* __restrict__ pooled,
                                              const u16* __restrict__ WB,
                                              const float* __restrict__ bias,
                                              float* __restrict__ proj) {
  const int rt = blockIdx.x, ctg = blockIdx.y;
  const int t = threadIdx.x, w = t >> 6, l = t & 63;
  const int lr = l & 15, lg = l >> 4;
  const int r0 = rt * 16, c0 = (ctg * 4 + w) * 16;

  const float* pa = pooled + (size_t)(r0 + lr) * HH + lg * 8;
  const u16* pw = WB + (size_t)(c0 + lr) * HH + lg * 8;
  f32x4 acc = (f32x4){0.f, 0.f, 0.f, 0.f};
#pragma unroll 4
  for (int slab = 0; slab < 64; ++slab) {
    f32x4 x0 = *(const f32x4*)(pa + slab * 32);
    f32x4 x1 = *(const f32x4*)(pa + slab * 32 + 4);
    short8 a;
#pragma unroll
    for (int j = 0; j < 4; ++j) {
      a[j] = (short)f2bf(x0[j]);
      a[j + 4] = (short)f2bf(x1[j]);
    }
    short8 bv = *(const short8*)(pw + slab * 32);
    acc = __builtin_amdgcn_mfma_f32_16x16x32_bf16(a, bv, acc, 0, 0, 0);
  }
  const float bs = bias[c0 + lr];
#pragma unroll
  for (int j = 0; j < 4; ++j)
    proj[(size_t)(r0 + lg * 4 + j) * DD + c0 + lr] = acc[j] + bs;
}

// ---------------------------------------------------------------------------
// k_ln: LayerNorm over D=1024, one block per row (exact ref math, f32).
// ---------------------------------------------------------------------------
__global__ __launch_bounds__(256) void k_ln(const float* __restrict__ proj,
                                            const float* __restrict__ gamma,
                                            const float* __restrict__ beta,
                                            float* __restrict__ out) {
  const int row = blockIdx.x, t = threadIdx.x;
  float4 v = ((const float4*)(proj + (size_t)row * DD))[t];
  float s1 = v.x + v.y + v.z + v.w;
  float s2 = v.x * v.x + v.y * v.y + v.z * v.z + v.w * v.w;
#pragma unroll
  for (int off = 1; off < 64; off <<= 1) {
    s1 += __shfl_xor(s1, off);
    s2 += __shfl_xor(s2, off);
  }
  __shared__ float a1[4], a2[4];
  if ((t & 63) == 0) { a1[t >> 6] = s1; a2[t >> 6] = s2; }
  __syncthreads();
  const float S1 = a1[0] + a1[1] + a1[2] + a1[3];
  const float S2 = a2[0] + a2[1] + a2[2] + a2[3];
  const float mu = S1 * (1.0f / DD);
  const float var = S2 * (1.0f / DD) - mu * mu;
  const float rs = rsqrtf(var + 1e-5f);
  float4 g = ((const float4*)gamma)[t];
  float4 be = ((const float4*)beta)[t];
  float4 o;
  o.x = (v.x - mu) * rs * g.x + be.x;
  o.y = (v.y - mu) * rs * g.y + be.y;
  o.z = (v.z - mu) * rs * g.z + be.z;
  o.w = (v.w - mu) * rs * g.w + be.w;
  ((float4*)(out + (size_t)row * DD))[t] = o;
}

// ---------------------------------------------------------------------------

extern "C" void kernel_launch(void* const* d_in, const int* in_sizes, int n_in,
                              void* d_out, int out_size, void* d_ws, size_t ws_size,
                              hipStream_t stream) {
  (void)in_sizes; (void)n_in; (void)out_size; (void)ws_size;
  const float* plan  = (const float*)d_in[0];
  const void*  own   = d_in[1];
  const float* W     = (const float*)d_in[2];
  const float* bias  = (const float*)d_in[3];
  const float* gamma = (const float*)d_in[4];
  const float* beta  = (const float*)d_in[5];
  float* out = (float*)d_out;
  char* ws = (char*)d_ws;

  u16*   w16    = (u16*)(ws + OFF_W16);
  u16*   WB     = (u16*)(ws + OFF_WB);
  float* pooled = (float*)(ws + OFF_POOLED);
  float* proj   = (float*)(ws + OFF_PROJ);

  k_prep<<<dim3(BB * KK + (HH / 64) * (DD / 64)), dim3(256), 0, stream>>>(own, w16, W, WB, pooled);
  k_pool<<<dim3(2, NSC, BB), dim3(1024), 0, stream>>>(plan, w16, pooled);
  k_proj<<<dim3(16, 16), dim3(256), 0, stream>>>(pooled, WB, bias, proj);
  k_ln<<<dim3(BB * KK), dim3(256), 0, stream>>>(proj, gamma, beta, out);
}